// Round 10
// baseline (95.243 us; speedup 1.0000x reference)
//
#include <hip/hip_runtime.h>

#define BHW   25088
#define HW    3136
#define DD    64
#define KNEG  100
#define NBLK2 (BHW / 4)   // 6272 blocks, 4 waves (n's) per block

typedef float fl4 __attribute__((ext_vector_type(4)));   // clang vector: OK for nontemporal builtins

#if __has_builtin(__builtin_amdgcn_sdot4)
#define HAVE_SDOT4 1
#else
#define HAVE_SDOT4 0
#endif

// int8 dot4: c += sum of signed-byte products (v_dot4_i32_i8 on gfx950)
__device__ __forceinline__ int dot4i8(uint32_t a, uint32_t b, int c) {
#if HAVE_SDOT4
    return __builtin_amdgcn_sdot4((int)a, (int)b, c, false);
#else
#pragma unroll
    for (int j = 0; j < 4; ++j) {
        c += (int)(int8_t)(a >> (8 * j)) * (int)(int8_t)(b >> (8 * j));
    }
    return c;
#endif
}

__device__ __forceinline__ uint32_t pack4i8(float a, float b, float c, float d) {
    const int ia = (int)rintf(a), ib = (int)rintf(b);
    const int ic = (int)rintf(c), id = (int)rintf(d);
    return (uint32_t)(ia & 0xff) | ((uint32_t)(ib & 0xff) << 8) |
           ((uint32_t)(ic & 0xff) << 16) | ((uint32_t)(id & 0xff) << 24);
}

// ---------------------------------------------------------------------------
// Kernel 1 (512 thr): normalize x1 rows -> xq (int8, q=round(127*x), row-major
// (n,64)), positive[n] in f32 (exact path). LDS tile-transpose with float4
// nontemporal staging loads (single-use stream; keep L2 clean for xq table).
// ---------------------------------------------------------------------------
__global__ __launch_bounds__(512) void k1_normalize(
    const float* __restrict__ x1, const float* __restrict__ x2,
    uint32_t* __restrict__ xq, float* __restrict__ pos)
{
    __shared__ float A[64][65];   // +1 pad: phase-2 column reads 2-way max (free)
    __shared__ float C[64][65];
    __shared__ float inv1[64];

    const int t   = threadIdx.x;
    const int b    = blockIdx.x / 49;
    const int tile = blockIdx.x % 49;
    const int hw0  = tile * 64;

    // stage: float4 loads, 16 lanes x 16B = 256B per row-group
    const fl4* p1v = (const fl4*)(x1 + (size_t)b * DD * HW + hw0);
    const fl4* p2v = (const fl4*)(x2 + (size_t)b * DD * HW + hw0);
    const int c4 = t & 15;        // float4 column within tile (hw = 4*c4..4*c4+3)
    const int dr = t >> 4;        // 0..31
    const int HW4 = HW / 4;       // row stride in float4
#pragma unroll
    for (int i = 0; i < 2; ++i) {
        const int row = i * 32 + dr;                 // d index
        const fl4 va = __builtin_nontemporal_load(&p1v[(size_t)row * HW4 + c4]);
        const fl4 vc = __builtin_nontemporal_load(&p2v[(size_t)row * HW4 + c4]);
        A[row][4 * c4 + 0] = va.x; A[row][4 * c4 + 1] = va.y;
        A[row][4 * c4 + 2] = va.z; A[row][4 * c4 + 3] = va.w;
        C[row][4 * c4 + 0] = vc.x; C[row][4 * c4 + 1] = vc.y;
        C[row][4 * c4 + 2] = vc.z; C[row][4 * c4 + 3] = vc.w;
    }
    __syncthreads();

    // phase 2: 512 threads = 64 rows x 8 d-chunks of 8 (8 lanes per row)
    const int l   = t & 63;
    const int qr  = t >> 6;             // wave id 0..7
    const int r   = qr * 8 + (l >> 3);  // row (hw) within tile
    const int sub = l & 7;              // d-chunk 0..7

    float na = 0.f, nc = 0.f;
#pragma unroll
    for (int j = 0; j < 8; ++j) {
        const int d = sub * 8 + j;
        const float a = A[d][r], cc = C[d][r];
        na += a * a;
        nc += cc * cc;
    }
    na += __shfl_xor(na, 1); na += __shfl_xor(na, 2); na += __shfl_xor(na, 4);
    nc += __shfl_xor(nc, 1); nc += __shfl_xor(nc, 2); nc += __shfl_xor(nc, 4);
    const float r1 = 1.0f / fmaxf(sqrtf(na), 1e-12f);
    const float rc = 1.0f / fmaxf(sqrtf(nc), 1e-12f);
    const float scale = r1 * rc;

    float p = 0.f;
#pragma unroll
    for (int j = 0; j < 8; ++j) {
        const int d = sub * 8 + j;
        p += __expf(A[d][r] * C[d][r] * scale);   // TEMP == 1
    }
    p += __shfl_xor(p, 1); p += __shfl_xor(p, 2); p += __shfl_xor(p, 4);

    if (sub == 0) {
        pos[b * HW + hw0 + r] = p;
        inv1[r] = r1;
    }
    __syncthreads();

    // phase 3: write int8 table row-major: 64 rows x 16 uint (4 int8 each).
    uint32_t* outb = xq + (size_t)(b * HW + hw0) * 16;
    const int cp     = t & 15;    // uint index -> d = 4cp..4cp+3
    const int rowsel = t >> 4;    // 0..31
#pragma unroll
    for (int i = 0; i < 2; ++i) {
        const int nl = i * 32 + rowsel;
        const float s = inv1[nl] * 127.0f;
        outb[(size_t)nl * 16 + cp] =
            pack4i8(A[4 * cp + 0][nl] * s, A[4 * cp + 1][nl] * s,
                    A[4 * cp + 2][nl] * s, A[4 * cp + 3][nl] * s);
    }
}

// ---------------------------------------------------------------------------
// Kernel 2: negative[n] = sum_k exp(dot64(xq[n], xq[idx[n,k]]) / 127^2).
// One wave per n; 4 lanes per negative (g=l>>2), lane c=l&3 reads one uint4
// (16 int8 = quarter row); each gathered row = exactly one 64B line.
// Table 1.6MB -> fully L2-resident per XCD. idx stream (10MB) loaded
// NONTEMPORAL so it doesn't evict the table from L2. All 7 gathers issued
// back-to-back (MLP). NO fences (R3: acq/rel flushes per-XCD L2), NO
// grid-wide same-address atomics (R6: coherent-point RMW serializes ~12ns
// each -> 150us tail; same math rules out cooperative grid.sync()).
// ---------------------------------------------------------------------------
__global__ __launch_bounds__(256) void k2_negative(
    const uint32_t* __restrict__ xq, const int* __restrict__ neg_idx,
    const float* __restrict__ pos, float* __restrict__ partials)
{
    __shared__ float wpart[4];

    const int t = threadIdx.x;
    const int w = t >> 6;         // wave id 0..3
    const int l = t & 63;
    const int n = blockIdx.x * 4 + w;
    const int g = l >> 2;         // negative group 0..15
    const int c = l & 3;          // 16B slot within 64B row

    const uint4* gp = (const uint4*)xq;   // 4 x uint4 per row
    const int* idxp = neg_idx + (size_t)n * KNEG;

    // ---- stage 1: indices (7 coalesced wave-reads, nontemporal) ----
    int rows[7];
#pragma unroll
    for (int i = 0; i < 7; ++i) {
        const int kidx = i * 16 + g;
        rows[i] = __builtin_nontemporal_load(&idxp[kidx < KNEG ? kidx : (KNEG - 1)]);
    }
    // ---- stage 2: all gathers in flight ----
    uint4 v[7];
#pragma unroll
    for (int i = 0; i < 7; ++i) {
        v[i] = gp[(size_t)rows[i] * 4 + c];
    }
    // query fragment: d in [16c,16c+16) of row n, already int8 -- no decode
    const uint4 qw = gp[(size_t)n * 4 + c];

    // ---- stage 3: compute ----
    const float inv1272 = 1.0f / 16129.0f;   // 1/127^2
    float acc = 0.f;
#pragma unroll
    for (int i = 0; i < 7; ++i) {
        int s = 0;
        s = dot4i8(v[i].x, qw.x, s);
        s = dot4i8(v[i].y, qw.y, s);
        s = dot4i8(v[i].z, qw.z, s);
        s = dot4i8(v[i].w, qw.w, s);
        s += __shfl_xor(s, 1);
        s += __shfl_xor(s, 2);     // 4-lane group holds full int dot
        const float e = __expf((float)s * inv1272);  // TEMP == 1
        acc += (i * 16 + g < KNEG) ? e : 0.f;
    }
    // lanes within a group hold identical acc; butterfly across 16 groups
    acc += __shfl_xor(acc, 4);
    acc += __shfl_xor(acc, 8);
    acc += __shfl_xor(acc, 16);
    acc += __shfl_xor(acc, 32);

    if (l == 0) wpart[w] = log1pf(acc / pos[n]);   // log(p+neg)-log(p)
    __syncthreads();
    if (t == 0) {
        __builtin_nontemporal_store(
            wpart[0] + wpart[1] + wpart[2] + wpart[3], &partials[blockIdx.x]);
    }
}

// ---------------------------------------------------------------------------
// Kernel 3 (1024 thr): reduce 6272 partials -> mean loss scalar.
// ---------------------------------------------------------------------------
__global__ __launch_bounds__(1024) void k3_reduce(
    const float* __restrict__ partials, float* __restrict__ out)
{
    __shared__ float s[1024];
    const int t = threadIdx.x;
    float a = 0.f;
    for (int i = t; i < NBLK2; i += 1024) a += partials[i];
    s[t] = a;
    __syncthreads();
    for (int off = 512; off > 0; off >>= 1) {
        if (t < off) s[t] += s[t + off];
        __syncthreads();
    }
    if (t == 0) out[0] = s[0] * (1.0f / (float)BHW);
}

extern "C" void kernel_launch(void* const* d_in, const int* in_sizes, int n_in,
                              void* d_out, int out_size, void* d_ws, size_t ws_size,
                              hipStream_t stream)
{
    const float* x1  = (const float*)d_in[0];
    const float* x2  = (const float*)d_in[1];
    const int*   neg = (const int*)d_in[2];
    float* out = (float*)d_out;

    char* ws = (char*)d_ws;
    uint32_t* xq    = (uint32_t*)ws;                            // 25088*64 int8 = 1.61 MB
    float* pos      = (float*)(ws + (size_t)BHW * DD);          // 25088 f32
    float* partials = (float*)(ws + (size_t)BHW * DD + BHW * 4);

    k1_normalize<<<8 * 49, 512, 0, stream>>>(x1, x2, xq, pos);
    k2_negative<<<NBLK2, 256, 0, stream>>>(xq, neg, pos, partials);
    k3_reduce<<<1, 1024, 0, stream>>>(partials, out);
}